// Round 1
// baseline (434.363 us; speedup 1.0000x reference)
//
#include <hip/hip_runtime.h>

#define N_NODES 20000
#define HID     256
#define DEG     32
#define TOPK    16

// ---------------------------------------------------------------------------
// GEMM: C[M,256] = A[M,256] @ W^T + b   (W row-major [256,256], C[n,j] = sum_k A[n,k]*W[j,k])
// 64x64 tile, BK=32, 256 threads, 4x4 micro-tile. Optional fused leaky-relu.
// ---------------------------------------------------------------------------
template<int RELU>
__global__ __launch_bounds__(256) void gemm_wt(
    const float* __restrict__ A, const float* __restrict__ W,
    const float* __restrict__ bias, float* __restrict__ C, int M)
{
    __shared__ float As[32][64];   // As[k][m]
    __shared__ float Bs[32][64];   // Bs[k][n] = W[colbase+n][k0+k]

    const int t = threadIdx.x;
    const int rowbase = blockIdx.x * 64;
    const int colbase = blockIdx.y * 64;
    const int tc = t & 15, tr = t >> 4;
    const int r0 = tr * 4, c0 = tc * 4;

    const int sk = (t & 7) * 4;   // k offset within tile (0,4,...,28)
    const int sm = t >> 3;        // 0..31

    float acc[4][4] = {};

    for (int k0 = 0; k0 < 256; k0 += 32) {
        // stage A tile (transposed into As[k][m]); guard rows >= M
        #pragma unroll
        for (int half = 0; half < 2; ++half) {
            int m   = sm + half * 32;
            int row = rowbase + m;
            float4 f = make_float4(0.f, 0.f, 0.f, 0.f);
            if (row < M) f = *(const float4*)(A + (size_t)row * 256 + k0 + sk);
            As[sk + 0][m] = f.x; As[sk + 1][m] = f.y;
            As[sk + 2][m] = f.z; As[sk + 3][m] = f.w;
        }
        // stage W tile: read along k (contiguous), write transposed
        #pragma unroll
        for (int half = 0; half < 2; ++half) {
            int nn = sm + half * 32;
            float4 f = *(const float4*)(W + (size_t)(colbase + nn) * 256 + k0 + sk);
            Bs[sk + 0][nn] = f.x; Bs[sk + 1][nn] = f.y;
            Bs[sk + 2][nn] = f.z; Bs[sk + 3][nn] = f.w;
        }
        __syncthreads();

        #pragma unroll
        for (int kk = 0; kk < 32; ++kk) {
            float4 a = *(const float4*)&As[kk][r0];
            float4 b = *(const float4*)&Bs[kk][c0];
            float av[4] = {a.x, a.y, a.z, a.w};
            float bv[4] = {b.x, b.y, b.z, b.w};
            #pragma unroll
            for (int i = 0; i < 4; ++i)
                #pragma unroll
                for (int j = 0; j < 4; ++j)
                    acc[i][j] = fmaf(av[i], bv[j], acc[i][j]);
        }
        __syncthreads();
    }

    // epilogue: add bias, optional leaky-relu, float4 stores
    #pragma unroll
    for (int i = 0; i < 4; ++i) {
        int row = rowbase + r0 + i;
        if (row >= M) break;
        float4 o;
        float* op = &o.x;
        #pragma unroll
        for (int j = 0; j < 4; ++j) {
            float x = acc[i][j] + bias[colbase + c0 + j];
            if (RELU) x = (x >= 0.f) ? x : 0.01f * x;
            op[j] = x;
        }
        *(float4*)(C + (size_t)row * 256 + colbase + c0) = o;
    }
}

// ---------------------------------------------------------------------------
// Attention: one block (256 thr) per node.
//   wave0: top-16 rank mask on edge weights, normalize -> wgt[32]
//   stage k rows of 32 neighbors into padded LDS
//   thread (d, h): score = <k[nbr[d],h,:], q[n,h,:]>, logit = score*w[d]/sqrt(32)
//   softmax over d (width-32 shuffles), attn -> LDS
//   thread t (= h*32+c): agg[n,t] = sum_d attn[d,h] * v[nbr[d], t]
// ---------------------------------------------------------------------------
__global__ __launch_bounds__(256) void attn_kernel(
    const float* __restrict__ q, const float* __restrict__ k,
    const float* __restrict__ v, const int* __restrict__ nbr,
    const float* __restrict__ ew, float* __restrict__ agg)
{
    __shared__ float qs[256];
    __shared__ float ks[32][257];   // +1 pad: score reads conflict-free
    __shared__ int   nb[32];
    __shared__ float ews[32];
    __shared__ float wgt[32];
    __shared__ float att[32 * 8];

    const int n = blockIdx.x;
    const int t = threadIdx.x;

    qs[t] = q[(size_t)n * 256 + t];
    if (t < 32) {
        nb[t]  = nbr[n * 32 + t];
        ews[t] = ew[n * 32 + t];
    }
    __syncthreads();

    // top-k mask + weight normalization (threads 0..31 = wave0 lanes 0..31)
    if (t < 32) {
        float my = ews[t];
        int cnt = 0;
        #pragma unroll
        for (int j = 0; j < 32; ++j) {
            float o = ews[j];
            cnt += (o > my || (o == my && j < t)) ? 1 : 0;
        }
        float w = (cnt < TOPK) ? my : 0.0f;
        float s = w;
        #pragma unroll
        for (int off = 16; off; off >>= 1) s += __shfl_xor(s, off, 32);
        wgt[t] = w / (s + 1e-5f);
    }

    // stage 32 neighbor k rows: group g = t/8 handles row g, 8 threads x 8 float4
    {
        const int r = t >> 3, l8 = t & 7;
        const float* krow = k + (size_t)nb[r] * 256;
        #pragma unroll
        for (int c8 = 0; c8 < 8; ++c8) {
            int c4 = (c8 * 8 + l8) * 4;
            float4 f = *(const float4*)(krow + c4);
            ks[r][c4 + 0] = f.x; ks[r][c4 + 1] = f.y;
            ks[r][c4 + 2] = f.z; ks[r][c4 + 3] = f.w;
        }
    }
    __syncthreads();

    const int d  = t & 31;
    const int hh = t >> 5;

    float sc = 0.f;
    #pragma unroll
    for (int i = 0; i < 32; ++i)
        sc = fmaf(ks[d][hh * 32 + i], qs[hh * 32 + i], sc);

    float logit = sc * wgt[d] * 0.17677669529663687f;  // * w / sqrt(32)

    float mx = logit;
    #pragma unroll
    for (int off = 16; off; off >>= 1) mx = fmaxf(mx, __shfl_xor(mx, off, 32));
    float e = expf(logit - mx);
    float ssum = e;
    #pragma unroll
    for (int off = 16; off; off >>= 1) ssum += __shfl_xor(ssum, off, 32);
    att[d * 8 + hh] = e / ssum;
    __syncthreads();

    // weighted v accumulation; col = t, rows gathered from global (coalesced per row)
    float acc = 0.f;
    #pragma unroll
    for (int dd = 0; dd < 32; ++dd)
        acc = fmaf(att[dd * 8 + hh], v[(size_t)nb[dd] * 256 + t], acc);

    agg[(size_t)n * 256 + t] = acc;
}

// ---------------------------------------------------------------------------
extern "C" void kernel_launch(void* const* d_in, const int* in_sizes, int n_in,
                              void* d_out, int out_size, void* d_ws, size_t ws_size,
                              hipStream_t stream)
{
    const float* h   = (const float*)d_in[0];
    const int*   nbr = (const int*)  d_in[1];
    const float* ew  = (const float*)d_in[2];
    const float* Wq  = (const float*)d_in[3];
    const float* bq  = (const float*)d_in[4];
    const float* Wk  = (const float*)d_in[5];
    const float* bk  = (const float*)d_in[6];
    const float* Wv  = (const float*)d_in[7];
    const float* bv  = (const float*)d_in[8];
    const float* Wo  = (const float*)d_in[9];
    const float* bo  = (const float*)d_in[10];
    float* out = (float*)d_out;

    const size_t NM = (size_t)N_NODES * HID;
    float* q   = (float*)d_ws;
    float* kk  = q  + NM;
    float* vv  = kk + NM;
    float* agg = vv + NM;

    dim3 blk(256);
    dim3 grid((N_NODES + 63) / 64, 4);

    gemm_wt<0><<<grid, blk, 0, stream>>>(h, Wq, bq, q,  N_NODES);
    gemm_wt<0><<<grid, blk, 0, stream>>>(h, Wk, bk, kk, N_NODES);
    gemm_wt<0><<<grid, blk, 0, stream>>>(h, Wv, bv, vv, N_NODES);
    attn_kernel<<<dim3(N_NODES), blk, 0, stream>>>(q, kk, vv, nbr, ew, agg);
    gemm_wt<1><<<grid, blk, 0, stream>>>(agg, Wo, bo, out, N_NODES);
}

// Round 2
// 299.470 us; speedup vs baseline: 1.4504x; 1.4504x over previous
//
#include <hip/hip_runtime.h>

#define N_NODES 20000
#define HID     256
#define DEG     32
#define TOPK    16

typedef __attribute__((ext_vector_type(8))) short short8;
typedef __attribute__((ext_vector_type(4))) float f32x4;

__device__ inline unsigned short f2bf(float f) {
    unsigned u = __float_as_uint(f);
    unsigned r = (u + 0x7FFFu + ((u >> 16) & 1u)) >> 16;  // RNE
    return (unsigned short)r;
}
__device__ inline float bf2f(unsigned short s) {
    return __uint_as_float(((unsigned)s) << 16);
}

// ---------------------------------------------------------------------------
// fp32 -> bf16 converters
// ---------------------------------------------------------------------------
__global__ __launch_bounds__(256) void convert_h_kernel(
    const float* __restrict__ src, unsigned short* __restrict__ dst, int n4)
{
    int i = blockIdx.x * 256 + threadIdx.x;
    if (i < n4) {
        float4 f = ((const float4*)src)[i];
        ushort4 o;
        o.x = f2bf(f.x); o.y = f2bf(f.y); o.z = f2bf(f.z); o.w = f2bf(f.w);
        ((ushort4*)dst)[i] = o;
    }
}

__global__ __launch_bounds__(256) void convert_w3_kernel(
    const float* __restrict__ a, const float* __restrict__ b, const float* __restrict__ c,
    unsigned short* __restrict__ da, unsigned short* __restrict__ db,
    unsigned short* __restrict__ dc, int n4)
{
    int i = blockIdx.x * 256 + threadIdx.x;
    if (i < n4) {
        float4 f = ((const float4*)a)[i];
        ushort4 o;
        o.x = f2bf(f.x); o.y = f2bf(f.y); o.z = f2bf(f.z); o.w = f2bf(f.w);
        ((ushort4*)da)[i] = o;
        f = ((const float4*)b)[i];
        o.x = f2bf(f.x); o.y = f2bf(f.y); o.z = f2bf(f.z); o.w = f2bf(f.w);
        ((ushort4*)db)[i] = o;
        f = ((const float4*)c)[i];
        o.x = f2bf(f.x); o.y = f2bf(f.y); o.z = f2bf(f.z); o.w = f2bf(f.w);
        ((ushort4*)dc)[i] = o;
    }
}

// ---------------------------------------------------------------------------
// bf16 MFMA GEMM: C[M,256] = bf16(A @ W^T + b), A/W/C bf16 (as ushort), bias fp32.
// 128x128 block tile, BK=64, 256 thr (4 waves, each 64x64), mfma 16x16x32.
// A-frag: lane holds A[m=lane&15][k=(lane>>4)*8 + j]; B-frag: W[n=lane&15][same k].
// C/D: col=lane&15, row=(lane>>4)*4+reg (verified mapping).
// ---------------------------------------------------------------------------
#define PADE 8
__global__ __launch_bounds__(256) void gemm_bf16(
    const unsigned short* __restrict__ A, const unsigned short* __restrict__ W,
    const float* __restrict__ bias, unsigned short* __restrict__ C, int M)
{
    __shared__ unsigned short As[128][64 + PADE];
    __shared__ unsigned short Ws[128][64 + PADE];

    const int t    = threadIdx.x;
    const int lane = t & 63;
    const int wave = t >> 6;
    const int wm   = (wave & 1) * 64;
    const int wn   = (wave >> 1) * 64;
    const int rowbase = blockIdx.x * 128;
    const int colbase = blockIdx.y * 128;

    f32x4 acc[4][4];
    #pragma unroll
    for (int i = 0; i < 4; ++i)
        #pragma unroll
        for (int j = 0; j < 4; ++j)
            acc[i][j] = (f32x4){0.f, 0.f, 0.f, 0.f};

    const int lm = lane & 15;
    const int q8 = (lane >> 4) * 8;

    for (int k0 = 0; k0 < 256; k0 += 64) {
        // stage A + W tiles: 128 rows x 8 chunks(16B) = 1024 chunks, 4 per thread
        #pragma unroll
        for (int cidx = 0; cidx < 4; ++cidx) {
            int idx = t + 256 * cidx;
            int row = idx >> 3;
            int col = (idx & 7) * 8;
            uint4 av = make_uint4(0u, 0u, 0u, 0u);
            int grow = rowbase + row;
            if (grow < M) av = *(const uint4*)(A + (size_t)grow * 256 + k0 + col);
            *(uint4*)&As[row][col] = av;
            uint4 wv = *(const uint4*)(W + (size_t)(colbase + row) * 256 + k0 + col);
            *(uint4*)&Ws[row][col] = wv;
        }
        __syncthreads();

        #pragma unroll
        for (int kk = 0; kk < 64; kk += 32) {
            short8 af[4], bfr[4];
            #pragma unroll
            for (int i = 0; i < 4; ++i)
                af[i] = *(const short8*)&As[wm + i * 16 + lm][kk + q8];
            #pragma unroll
            for (int j = 0; j < 4; ++j)
                bfr[j] = *(const short8*)&Ws[wn + j * 16 + lm][kk + q8];
            #pragma unroll
            for (int i = 0; i < 4; ++i)
                #pragma unroll
                for (int j = 0; j < 4; ++j)
                    acc[i][j] = __builtin_amdgcn_mfma_f32_16x16x32_bf16(
                        af[i], bfr[j], acc[i][j], 0, 0, 0);
        }
        __syncthreads();
    }

    const int lq = lane >> 4;
    #pragma unroll
    for (int j = 0; j < 4; ++j) {
        int col = colbase + wn + j * 16 + lm;
        float bv = bias[col];
        #pragma unroll
        for (int i = 0; i < 4; ++i) {
            #pragma unroll
            for (int r = 0; r < 4; ++r) {
                int row = rowbase + wm + i * 16 + lq * 4 + r;
                if (row < M) C[(size_t)row * 256 + col] = f2bf(acc[i][j][r] + bv);
            }
        }
    }
}

// ---------------------------------------------------------------------------
// fp32 GEMM (o-projection, fused leaky-relu): C = A@W^T + b
// ---------------------------------------------------------------------------
template<int RELU>
__global__ __launch_bounds__(256) void gemm_wt(
    const float* __restrict__ A, const float* __restrict__ W,
    const float* __restrict__ bias, float* __restrict__ C, int M)
{
    __shared__ float As[32][64];
    __shared__ float Bs[32][64];

    const int t = threadIdx.x;
    const int rowbase = blockIdx.x * 64;
    const int colbase = blockIdx.y * 64;
    const int tc = t & 15, tr = t >> 4;
    const int r0 = tr * 4, c0 = tc * 4;
    const int sk = (t & 7) * 4;
    const int sm = t >> 3;

    float acc[4][4] = {};

    for (int k0 = 0; k0 < 256; k0 += 32) {
        #pragma unroll
        for (int half = 0; half < 2; ++half) {
            int m = sm + half * 32;
            int row = rowbase + m;
            float4 f = make_float4(0.f, 0.f, 0.f, 0.f);
            if (row < M) f = *(const float4*)(A + (size_t)row * 256 + k0 + sk);
            As[sk + 0][m] = f.x; As[sk + 1][m] = f.y;
            As[sk + 2][m] = f.z; As[sk + 3][m] = f.w;
        }
        #pragma unroll
        for (int half = 0; half < 2; ++half) {
            int nn = sm + half * 32;
            float4 f = *(const float4*)(W + (size_t)(colbase + nn) * 256 + k0 + sk);
            Bs[sk + 0][nn] = f.x; Bs[sk + 1][nn] = f.y;
            Bs[sk + 2][nn] = f.z; Bs[sk + 3][nn] = f.w;
        }
        __syncthreads();

        #pragma unroll
        for (int kk = 0; kk < 32; ++kk) {
            float4 a = *(const float4*)&As[kk][r0];
            float4 b = *(const float4*)&Bs[kk][c0];
            float av[4] = {a.x, a.y, a.z, a.w};
            float bv[4] = {b.x, b.y, b.z, b.w};
            #pragma unroll
            for (int i = 0; i < 4; ++i)
                #pragma unroll
                for (int j = 0; j < 4; ++j)
                    acc[i][j] = fmaf(av[i], bv[j], acc[i][j]);
        }
        __syncthreads();
    }

    #pragma unroll
    for (int i = 0; i < 4; ++i) {
        int row = rowbase + r0 + i;
        if (row >= M) break;
        float4 o;
        float* op = &o.x;
        #pragma unroll
        for (int j = 0; j < 4; ++j) {
            float x = acc[i][j] + bias[colbase + c0 + j];
            if (RELU) x = (x >= 0.f) ? x : 0.01f * x;
            op[j] = x;
        }
        *(float4*)(C + (size_t)row * 256 + colbase + c0) = o;
    }
}

// ---------------------------------------------------------------------------
// Attention over 32 neighbors, top-16 edge-weight mask. q/k/v bf16, agg fp32.
// ---------------------------------------------------------------------------
__global__ __launch_bounds__(256) void attn_kernel(
    const unsigned short* __restrict__ q, const unsigned short* __restrict__ k,
    const unsigned short* __restrict__ v, const int* __restrict__ nbr,
    const float* __restrict__ ew, float* __restrict__ agg)
{
    __shared__ float qs[256];
    __shared__ float ks[32][257];
    __shared__ int   nb[32];
    __shared__ float ews[32];
    __shared__ float wgt[32];
    __shared__ float att[32 * 8];

    const int n = blockIdx.x;
    const int t = threadIdx.x;

    qs[t] = bf2f(q[(size_t)n * 256 + t]);
    if (t < 32) {
        nb[t]  = nbr[n * 32 + t];
        ews[t] = ew[n * 32 + t];
    }
    __syncthreads();

    // top-k mask + normalize (wave0 lanes 0..31)
    if (t < 32) {
        float my = ews[t];
        int cnt = 0;
        #pragma unroll
        for (int j = 0; j < 32; ++j) {
            float o = ews[j];
            cnt += (o > my || (o == my && j < t)) ? 1 : 0;
        }
        float w = (cnt < TOPK) ? my : 0.0f;
        float s = w;
        #pragma unroll
        for (int off = 16; off; off >>= 1) s += __shfl_xor(s, off, 32);
        wgt[t] = w / (s + 1e-5f);
    }

    // stage 32 neighbor k rows (bf16 -> fp32 LDS): row = t/8, 8 thr x 4 chunks(8 elems)
    {
        const int r = t >> 3, l8 = t & 7;
        const unsigned short* krow = k + (size_t)nb[r] * 256;
        #pragma unroll
        for (int c = 0; c < 4; ++c) {
            int col = (l8 + 8 * c) * 8;
            uint4 u = *(const uint4*)(krow + col);
            unsigned uu[4] = {u.x, u.y, u.z, u.w};
            #pragma unroll
            for (int m = 0; m < 4; ++m) {
                ks[r][col + 2 * m]     = __uint_as_float(uu[m] << 16);
                ks[r][col + 2 * m + 1] = __uint_as_float(uu[m] & 0xFFFF0000u);
            }
        }
    }
    __syncthreads();

    const int d  = t & 31;
    const int hh = t >> 5;

    float sc = 0.f;
    #pragma unroll
    for (int i = 0; i < 32; ++i)
        sc = fmaf(ks[d][hh * 32 + i], qs[hh * 32 + i], sc);

    float logit = sc * wgt[d] * 0.17677669529663687f;  // * w / sqrt(32)

    float mx = logit;
    #pragma unroll
    for (int off = 16; off; off >>= 1) mx = fmaxf(mx, __shfl_xor(mx, off, 32));
    float e = expf(logit - mx);
    float ssum = e;
    #pragma unroll
    for (int off = 16; off; off >>= 1) ssum += __shfl_xor(ssum, off, 32);
    att[d * 8 + hh] = e / ssum;
    __syncthreads();

    float acc = 0.f;
    #pragma unroll
    for (int dd = 0; dd < 32; ++dd)
        acc = fmaf(att[dd * 8 + hh], bf2f(v[(size_t)nb[dd] * 256 + t]), acc);

    agg[(size_t)n * 256 + t] = acc;
}

// ---------------------------------------------------------------------------
extern "C" void kernel_launch(void* const* d_in, const int* in_sizes, int n_in,
                              void* d_out, int out_size, void* d_ws, size_t ws_size,
                              hipStream_t stream)
{
    const float* h   = (const float*)d_in[0];
    const int*   nbr = (const int*)  d_in[1];
    const float* ew  = (const float*)d_in[2];
    const float* Wq  = (const float*)d_in[3];
    const float* bq  = (const float*)d_in[4];
    const float* Wk  = (const float*)d_in[5];
    const float* bk  = (const float*)d_in[6];
    const float* Wv  = (const float*)d_in[7];
    const float* bv  = (const float*)d_in[8];
    const float* Wo  = (const float*)d_in[9];
    const float* bo  = (const float*)d_in[10];
    float* out = (float*)d_out;

    const size_t NM = (size_t)N_NODES * HID;   // 5,120,000
    char* ws = (char*)d_ws;
    unsigned short* hb  = (unsigned short*)ws;                 ws += NM * 2;
    unsigned short* qb  = (unsigned short*)ws;                 ws += NM * 2;
    unsigned short* kb  = (unsigned short*)ws;                 ws += NM * 2;
    unsigned short* vb  = (unsigned short*)ws;                 ws += NM * 2;
    unsigned short* Wqb = (unsigned short*)ws;                 ws += 65536 * 2;
    unsigned short* Wkb = (unsigned short*)ws;                 ws += 65536 * 2;
    unsigned short* Wvb = (unsigned short*)ws;                 ws += 65536 * 2;
    float* agg = (float*)ws;

    dim3 blk(256);

    convert_h_kernel<<<dim3((int)(NM / 4 + 255) / 256), blk, 0, stream>>>(h, hb, (int)(NM / 4));
    convert_w3_kernel<<<dim3(64), blk, 0, stream>>>(Wq, Wk, Wv, Wqb, Wkb, Wvb, 16384);

    dim3 ggrid((N_NODES + 127) / 128, 2);
    gemm_bf16<<<ggrid, blk, 0, stream>>>(hb, Wqb, bq, qb, N_NODES);
    gemm_bf16<<<ggrid, blk, 0, stream>>>(hb, Wkb, bk, kb, N_NODES);
    gemm_bf16<<<ggrid, blk, 0, stream>>>(hb, Wvb, bv, vb, N_NODES);

    attn_kernel<<<dim3(N_NODES), blk, 0, stream>>>(qb, kb, vb, nbr, ew, agg);

    dim3 ogrid((N_NODES + 63) / 64, 4);
    gemm_wt<1><<<ogrid, blk, 0, stream>>>(agg, Wo, bo, out, N_NODES);
}

// Round 3
// 233.273 us; speedup vs baseline: 1.8620x; 1.2838x over previous
//
#include <hip/hip_runtime.h>

#define N_NODES 20000
#define HID     256
#define DEG     32
#define TOPK    16

typedef __attribute__((ext_vector_type(8))) short short8;
typedef __attribute__((ext_vector_type(4))) float f32x4;

__device__ inline unsigned short f2bf(float f) {
    unsigned u = __float_as_uint(f);
    unsigned r = (u + 0x7FFFu + ((u >> 16) & 1u)) >> 16;  // RNE
    return (unsigned short)r;
}
__device__ inline float bf2f(unsigned short s) {
    return __uint_as_float(((unsigned)s) << 16);
}

// ---------------------------------------------------------------------------
// fp32 -> bf16 converters
// ---------------------------------------------------------------------------
__global__ __launch_bounds__(256) void convert_kernel(
    const float* __restrict__ src, unsigned short* __restrict__ dst, int n4)
{
    int i = blockIdx.x * 256 + threadIdx.x;
    if (i < n4) {
        float4 f = ((const float4*)src)[i];
        ushort4 o;
        o.x = f2bf(f.x); o.y = f2bf(f.y); o.z = f2bf(f.z); o.w = f2bf(f.w);
        ((ushort4*)dst)[i] = o;
    }
}

__global__ __launch_bounds__(256) void convert_w3_kernel(
    const float* __restrict__ a, const float* __restrict__ b, const float* __restrict__ c,
    unsigned short* __restrict__ da, unsigned short* __restrict__ db,
    unsigned short* __restrict__ dc, int n4)
{
    int i = blockIdx.x * 256 + threadIdx.x;
    if (i < n4) {
        float4 f = ((const float4*)a)[i];
        ushort4 o;
        o.x = f2bf(f.x); o.y = f2bf(f.y); o.z = f2bf(f.z); o.w = f2bf(f.w);
        ((ushort4*)da)[i] = o;
        f = ((const float4*)b)[i];
        o.x = f2bf(f.x); o.y = f2bf(f.y); o.z = f2bf(f.z); o.w = f2bf(f.w);
        ((ushort4*)db)[i] = o;
        f = ((const float4*)c)[i];
        o.x = f2bf(f.x); o.y = f2bf(f.y); o.z = f2bf(f.z); o.w = f2bf(f.w);
        ((ushort4*)dc)[i] = o;
    }
}

// ---------------------------------------------------------------------------
// bf16 MFMA GEMM: C[M,256] = A @ W^T + b. A/W bf16 (ushort), bias fp32.
// OUTF32=0 -> bf16 out; OUTF32=1 -> fp32 out (+leaky relu if RELU).
// 128x128 block tile, BK=64, 256 thr (4 waves, 64x64 each), mfma 16x16x32.
// ---------------------------------------------------------------------------
#define PADE 8
template<int RELU, int OUTF32>
__global__ __launch_bounds__(256) void gemm_bf16(
    const unsigned short* __restrict__ A, const unsigned short* __restrict__ W,
    const float* __restrict__ bias, unsigned short* __restrict__ Cb,
    float* __restrict__ Cf, int M)
{
    __shared__ unsigned short As[128][64 + PADE];
    __shared__ unsigned short Ws[128][64 + PADE];

    const int t    = threadIdx.x;
    const int lane = t & 63;
    const int wave = t >> 6;
    const int wm   = (wave & 1) * 64;
    const int wn   = (wave >> 1) * 64;
    const int rowbase = blockIdx.x * 128;
    const int colbase = blockIdx.y * 128;

    f32x4 acc[4][4];
    #pragma unroll
    for (int i = 0; i < 4; ++i)
        #pragma unroll
        for (int j = 0; j < 4; ++j)
            acc[i][j] = (f32x4){0.f, 0.f, 0.f, 0.f};

    const int lm = lane & 15;
    const int q8 = (lane >> 4) * 8;

    for (int k0 = 0; k0 < 256; k0 += 64) {
        #pragma unroll
        for (int cidx = 0; cidx < 4; ++cidx) {
            int idx = t + 256 * cidx;
            int row = idx >> 3;
            int col = (idx & 7) * 8;
            uint4 av = make_uint4(0u, 0u, 0u, 0u);
            int grow = rowbase + row;
            if (grow < M) av = *(const uint4*)(A + (size_t)grow * 256 + k0 + col);
            *(uint4*)&As[row][col] = av;
            uint4 wv = *(const uint4*)(W + (size_t)(colbase + row) * 256 + k0 + col);
            *(uint4*)&Ws[row][col] = wv;
        }
        __syncthreads();

        #pragma unroll
        for (int kk = 0; kk < 64; kk += 32) {
            short8 af[4], bfr[4];
            #pragma unroll
            for (int i = 0; i < 4; ++i)
                af[i] = *(const short8*)&As[wm + i * 16 + lm][kk + q8];
            #pragma unroll
            for (int j = 0; j < 4; ++j)
                bfr[j] = *(const short8*)&Ws[wn + j * 16 + lm][kk + q8];
            #pragma unroll
            for (int i = 0; i < 4; ++i)
                #pragma unroll
                for (int j = 0; j < 4; ++j)
                    acc[i][j] = __builtin_amdgcn_mfma_f32_16x16x32_bf16(
                        af[i], bfr[j], acc[i][j], 0, 0, 0);
        }
        __syncthreads();
    }

    const int lq = lane >> 4;
    #pragma unroll
    for (int j = 0; j < 4; ++j) {
        int col = colbase + wn + j * 16 + lm;
        float bv = bias[col];
        #pragma unroll
        for (int i = 0; i < 4; ++i) {
            #pragma unroll
            for (int r = 0; r < 4; ++r) {
                int row = rowbase + wm + i * 16 + lq * 4 + r;
                if (row < M) {
                    float x = acc[i][j][r] + bv;
                    if (OUTF32) {
                        if (RELU) x = (x >= 0.f) ? x : 0.01f * x;
                        Cf[(size_t)row * 256 + col] = x;
                    } else {
                        Cb[(size_t)row * 256 + col] = f2bf(x);
                    }
                }
            }
        }
    }
}

// fused q/k/v GEMM: blockIdx.z selects weight/bias/output
__global__ __launch_bounds__(256) void gemm_qkv(
    const unsigned short* __restrict__ A,
    const unsigned short* __restrict__ Wq, const unsigned short* __restrict__ Wk,
    const unsigned short* __restrict__ Wv,
    const float* __restrict__ bq, const float* __restrict__ bk,
    const float* __restrict__ bv,
    unsigned short* __restrict__ Cq, unsigned short* __restrict__ Ck,
    unsigned short* __restrict__ Cv, int M)
{
    __shared__ unsigned short As[128][64 + PADE];
    __shared__ unsigned short Ws[128][64 + PADE];

    const int z = blockIdx.z;
    const unsigned short* W = (z == 0) ? Wq : (z == 1) ? Wk : Wv;
    const float* bias        = (z == 0) ? bq : (z == 1) ? bk : bv;
    unsigned short* C        = (z == 0) ? Cq : (z == 1) ? Ck : Cv;

    const int t    = threadIdx.x;
    const int lane = t & 63;
    const int wave = t >> 6;
    const int wm   = (wave & 1) * 64;
    const int wn   = (wave >> 1) * 64;
    const int rowbase = blockIdx.x * 128;
    const int colbase = blockIdx.y * 128;

    f32x4 acc[4][4];
    #pragma unroll
    for (int i = 0; i < 4; ++i)
        #pragma unroll
        for (int j = 0; j < 4; ++j)
            acc[i][j] = (f32x4){0.f, 0.f, 0.f, 0.f};

    const int lm = lane & 15;
    const int q8 = (lane >> 4) * 8;

    for (int k0 = 0; k0 < 256; k0 += 64) {
        #pragma unroll
        for (int cidx = 0; cidx < 4; ++cidx) {
            int idx = t + 256 * cidx;
            int row = idx >> 3;
            int col = (idx & 7) * 8;
            uint4 av = make_uint4(0u, 0u, 0u, 0u);
            int grow = rowbase + row;
            if (grow < M) av = *(const uint4*)(A + (size_t)grow * 256 + k0 + col);
            *(uint4*)&As[row][col] = av;
            uint4 wv = *(const uint4*)(W + (size_t)(colbase + row) * 256 + k0 + col);
            *(uint4*)&Ws[row][col] = wv;
        }
        __syncthreads();

        #pragma unroll
        for (int kk = 0; kk < 64; kk += 32) {
            short8 af[4], bfr[4];
            #pragma unroll
            for (int i = 0; i < 4; ++i)
                af[i] = *(const short8*)&As[wm + i * 16 + lm][kk + q8];
            #pragma unroll
            for (int j = 0; j < 4; ++j)
                bfr[j] = *(const short8*)&Ws[wn + j * 16 + lm][kk + q8];
            #pragma unroll
            for (int i = 0; i < 4; ++i)
                #pragma unroll
                for (int j = 0; j < 4; ++j)
                    acc[i][j] = __builtin_amdgcn_mfma_f32_16x16x32_bf16(
                        af[i], bfr[j], acc[i][j], 0, 0, 0);
        }
        __syncthreads();
    }

    const int lq = lane >> 4;
    #pragma unroll
    for (int j = 0; j < 4; ++j) {
        int col = colbase + wn + j * 16 + lm;
        float bv2 = bias[col];
        #pragma unroll
        for (int i = 0; i < 4; ++i) {
            #pragma unroll
            for (int r = 0; r < 4; ++r) {
                int row = rowbase + wm + i * 16 + lq * 4 + r;
                if (row < M) C[(size_t)row * 256 + col] = f2bf(acc[i][j][r] + bv2);
            }
        }
    }
}

// ---------------------------------------------------------------------------
// Attention v3: no k/v LDS staging. One block (256 thr) per node.
// thread (d,hh): reads 64B k-slice via 4x uint4 from global; softmax over d;
// agg: thread t = col, scalar bf16 gather of v. LDS ~2.5KB -> full occupancy.
// ---------------------------------------------------------------------------
__global__ __launch_bounds__(256) void attn_kernel(
    const unsigned short* __restrict__ q, const unsigned short* __restrict__ k,
    const unsigned short* __restrict__ v, const int* __restrict__ nbr,
    const float* __restrict__ ew, unsigned short* __restrict__ agg)
{
    __shared__ float qs[256];
    __shared__ int   nb[32];
    __shared__ float wgt[32];
    __shared__ float att[256];

    const int n = blockIdx.x;
    const int t = threadIdx.x;

    qs[t] = bf2f(q[(size_t)n * 256 + t]);

    if (t < 32) {
        nb[t] = nbr[n * 32 + t];
        float my = ew[n * 32 + t];
        int cnt = 0;
        #pragma unroll
        for (int j = 0; j < 32; ++j) {
            float o = __shfl(my, j, 32);
            cnt += (o > my || (o == my && j < t)) ? 1 : 0;
        }
        float w = (cnt < TOPK) ? my : 0.0f;
        float s = w;
        #pragma unroll
        for (int off = 16; off; off >>= 1) s += __shfl_xor(s, off, 32);
        wgt[t] = w / (s + 1e-5f);
    }
    __syncthreads();

    const int d  = t & 31;
    const int hh = t >> 5;

    // score: 64B contiguous k-slice, 4x uint4
    float sc = 0.f;
    {
        const unsigned short* krow = k + (size_t)nb[d] * 256 + hh * 32;
        const float* qp = &qs[hh * 32];
        #pragma unroll
        for (int m = 0; m < 4; ++m) {
            uint4 kv = *(const uint4*)(krow + m * 8);
            const float* qq = qp + m * 8;
            sc = fmaf(__uint_as_float(kv.x << 16),         qq[0], sc);
            sc = fmaf(__uint_as_float(kv.x & 0xFFFF0000u), qq[1], sc);
            sc = fmaf(__uint_as_float(kv.y << 16),         qq[2], sc);
            sc = fmaf(__uint_as_float(kv.y & 0xFFFF0000u), qq[3], sc);
            sc = fmaf(__uint_as_float(kv.z << 16),         qq[4], sc);
            sc = fmaf(__uint_as_float(kv.z & 0xFFFF0000u), qq[5], sc);
            sc = fmaf(__uint_as_float(kv.w << 16),         qq[6], sc);
            sc = fmaf(__uint_as_float(kv.w & 0xFFFF0000u), qq[7], sc);
        }
    }

    float logit = sc * wgt[d] * 0.17677669529663687f;  // * w / sqrt(32)

    float mx = logit;
    #pragma unroll
    for (int off = 16; off; off >>= 1) mx = fmaxf(mx, __shfl_xor(mx, off, 32));
    float e = expf(logit - mx);
    float ssum = e;
    #pragma unroll
    for (int off = 16; off; off >>= 1) ssum += __shfl_xor(ssum, off, 32);
    att[hh * 32 + d] = e / ssum;
    __syncthreads();

    // agg: thread t = col; scalar bf16 gather over 32 neighbor rows
    float acc = 0.f;
    #pragma unroll
    for (int dd = 0; dd < 32; ++dd) {
        float vv = bf2f(v[(size_t)nb[dd] * 256 + t]);
        acc = fmaf(att[hh * 32 + dd], vv, acc);
    }
    agg[(size_t)n * 256 + t] = f2bf(acc);
}

// ---------------------------------------------------------------------------
extern "C" void kernel_launch(void* const* d_in, const int* in_sizes, int n_in,
                              void* d_out, int out_size, void* d_ws, size_t ws_size,
                              hipStream_t stream)
{
    const float* h   = (const float*)d_in[0];
    const int*   nbr = (const int*)  d_in[1];
    const float* ew  = (const float*)d_in[2];
    const float* Wq  = (const float*)d_in[3];
    const float* bq  = (const float*)d_in[4];
    const float* Wk  = (const float*)d_in[5];
    const float* bk  = (const float*)d_in[6];
    const float* Wv  = (const float*)d_in[7];
    const float* bv  = (const float*)d_in[8];
    const float* Wo  = (const float*)d_in[9];
    const float* bo  = (const float*)d_in[10];
    float* out = (float*)d_out;

    const size_t NM = (size_t)N_NODES * HID;   // 5,120,000
    char* ws = (char*)d_ws;
    unsigned short* hb   = (unsigned short*)ws; ws += NM * 2;
    unsigned short* qb   = (unsigned short*)ws; ws += NM * 2;
    unsigned short* kb   = (unsigned short*)ws; ws += NM * 2;
    unsigned short* vb   = (unsigned short*)ws; ws += NM * 2;
    unsigned short* aggb = (unsigned short*)ws; ws += NM * 2;
    unsigned short* Wqb  = (unsigned short*)ws; ws += 65536 * 2;
    unsigned short* Wkb  = (unsigned short*)ws; ws += 65536 * 2;
    unsigned short* Wvb  = (unsigned short*)ws; ws += 65536 * 2;
    unsigned short* Wob  = (unsigned short*)ws; ws += 65536 * 2;

    dim3 blk(256);

    convert_kernel<<<dim3((int)(NM / 4 + 255) / 256), blk, 0, stream>>>(h, hb, (int)(NM / 4));
    convert_kernel<<<dim3(64), blk, 0, stream>>>(Wo, Wob, 16384);
    convert_w3_kernel<<<dim3(64), blk, 0, stream>>>(Wq, Wk, Wv, Wqb, Wkb, Wvb, 16384);

    dim3 qkvgrid((N_NODES + 127) / 128, 2, 3);
    gemm_qkv<<<qkvgrid, blk, 0, stream>>>(hb, Wqb, Wkb, Wvb, bq, bk, bv,
                                          qb, kb, vb, N_NODES);

    attn_kernel<<<dim3(N_NODES), blk, 0, stream>>>(qb, kb, vb, nbr, ew, aggb);

    dim3 ogrid((N_NODES + 127) / 128, 2);
    gemm_bf16<1, 1><<<ogrid, blk, 0, stream>>>(aggb, Wob, bo, nullptr, out, N_NODES);
}